// Round 4
// baseline (150.693 us; speedup 1.0000x reference)
//
#include <hip/hip_runtime.h>

// CompositeLoss: single-pass fused masked reduction over (2,3,128,128,128).
// 13 partial sums (padded to 16 per block in d_ws):
//  0:M  1:Mx(d) 2:My(h) 3:Mz(w)  4:Smae 5:Smse 6:Sbg
//  7:Sgx 8:Sgy 9:Sgz  10:Stx 11:Sty 12:Stz
// R4: 8 contiguous W-floats per thread (2x float4) -> 2x per-thread MLP,
//     half the blocks, W-boundary scalar loads cut from 3/group to 1/thread.
#define NACC 13
#define NPAD 16
#define NBLOCKS 2048   // 2^19 threads / 256

struct F8 { float f[8]; };

__device__ __forceinline__ float4 ld4(const float* p) {
    return *reinterpret_cast<const float4*>(p);
}
__device__ __forceinline__ F8 ld8(const float* p) {
    F8 r;
    const float4 a = ld4(p), b = ld4(p + 4);
    r.f[0] = a.x; r.f[1] = a.y; r.f[2] = a.z; r.f[3] = a.w;
    r.f[4] = b.x; r.f[5] = b.y; r.f[6] = b.z; r.f[7] = b.w;
    return r;
}
__device__ __forceinline__ F8 zero8() {
    F8 r;
#pragma unroll
    for (int i = 0; i < 8; ++i) r.f[i] = 0.f;
    return r;
}

__global__ __launch_bounds__(256) void loss_main(
    const float* __restrict__ pred, const float* __restrict__ target,
    const float* __restrict__ mask, float* __restrict__ partials)
{
    float acc[NACC];
#pragma unroll
    for (int k = 0; k < NACC; ++k) acc[k] = 0.f;

    // thread owns (b, d, h, w..w+7): 2*128*128*16 = 2^19 threads
    const int g  = blockIdx.x * 256 + threadIdx.x;
    const int w8 = g & 15;
    const int h  = (g >> 4) & 127;
    const int d  = (g >> 11) & 127;
    const int b  = g >> 18;
    const int w  = w8 << 3;
    const int mb  = b * 2097152 + d * 16384 + h * 128 + w; // mask index
    const int pb0 = b * 6291456 + d * 16384 + h * 128 + w; // pred/target base (c=0)
    const bool hw = w8 < 15, hh = h < 127, hd = d < 127;

    const F8    m0  = ld8(mask + mb);
    const float m8w = hw ? mask[mb + 8] : 0.f;
    const F8    mh  = hh ? ld8(mask + mb + 128)   : zero8();
    const F8    md  = hd ? ld8(mask + mb + 16384) : zero8();

    // pairwise mins (binary mask -> AND); zero-filled neighbors kill OOB terms
    float mz[8], my[8], mx[8];
#pragma unroll
    for (int i = 0; i < 8; ++i) {
        const float nw = (i < 7) ? m0.f[i + 1] : m8w;
        mz[i] = fminf(m0.f[i], nw);
        my[i] = fminf(m0.f[i], mh.f[i]);
        mx[i] = fminf(m0.f[i], md.f[i]);
        acc[0] += m0.f[i];
        acc[1] += mx[i];
        acc[2] += my[i];
        acc[3] += mz[i];
    }

#pragma unroll
    for (int c = 0; c < 3; ++c) {
        const int pb = pb0 + c * 2097152;
        const F8 p0 = ld8(pred + pb);
        const F8 t0 = ld8(target + pb);
        float p8 = 0.f, t8 = 0.f;
        if (hw) { p8 = pred[pb + 8]; t8 = target[pb + 8]; }
        const F8 ph = hh ? ld8(pred + pb + 128)     : zero8();
        const F8 th = hh ? ld8(target + pb + 128)   : zero8();
        const F8 pd = hd ? ld8(pred + pb + 16384)   : zero8();
        const F8 td = hd ? ld8(target + pb + 16384) : zero8();

        float e[9];
#pragma unroll
        for (int i = 0; i < 8; ++i) e[i] = p0.f[i] - t0.f[i];
        e[8] = p8 - t8;

#pragma unroll
        for (int i = 0; i < 8; ++i) {
            acc[4] += fabsf(e[i]) * m0.f[i];
            acc[5] += e[i] * e[i] * m0.f[i];
            acc[6] += fabsf(p0.f[i]) * (1.f - m0.f[i]);
            // W direction (reference dz)
            const float pn = (i < 7) ? p0.f[i + 1] : p8;
            acc[9]  += fabsf(e[i + 1] - e[i]) * mz[i];
            acc[12] += fabsf(pn - p0.f[i]) * mz[i];
            // H direction (reference dy)
            acc[8]  += fabsf((ph.f[i] - th.f[i]) - e[i]) * my[i];
            acc[11] += fabsf(ph.f[i] - p0.f[i]) * my[i];
            // D direction (reference dx)
            acc[7]  += fabsf((pd.f[i] - td.f[i]) - e[i]) * mx[i];
            acc[10] += fabsf(pd.f[i] - p0.f[i]) * mx[i];
        }
    }

    // wave (64) shuffle reduce -> LDS -> padded per-block row [block][16]
    const int lane = threadIdx.x & 63;
    const int wave = threadIdx.x >> 6;
    __shared__ float red[4][NACC];
#pragma unroll
    for (int k = 0; k < NACC; ++k) {
        float v = acc[k];
        for (int o = 32; o > 0; o >>= 1) v += __shfl_down(v, o, 64);
        if (lane == 0) red[wave][k] = v;
    }
    __syncthreads();
    if (threadIdx.x < NPAD) {
        const int k = threadIdx.x;
        const float v = (k < NACC)
            ? red[0][k] + red[1][k] + red[2][k] + red[3][k] : 0.f;
        partials[blockIdx.x * NPAD + k] = v;  // d_ws is poisoned: write all 16
    }
}

__global__ __launch_bounds__(1024) void loss_final(
    const float* __restrict__ partials, float* __restrict__ out)
{
    // 1024 threads; thread t owns rows t and t+1024. 8 independent float4
    // loads per thread -> latency fully overlapped.
    float4 a0 = make_float4(0, 0, 0, 0), a1 = a0, a2 = a0, a3 = a0;
#pragma unroll
    for (int i = 0; i < 2; ++i) {
        const float* row = partials + (threadIdx.x + (i << 10)) * NPAD;
        const float4 r0 = ld4(row);     const float4 r1 = ld4(row + 4);
        const float4 r2 = ld4(row + 8); const float4 r3 = ld4(row + 12);
        a0.x += r0.x; a0.y += r0.y; a0.z += r0.z; a0.w += r0.w;
        a1.x += r1.x; a1.y += r1.y; a1.z += r1.z; a1.w += r1.w;
        a2.x += r2.x; a2.y += r2.y; a2.z += r2.z; a2.w += r2.w;
        a3.x += r3.x; a3.y += r3.y; a3.z += r3.z; a3.w += r3.w;
    }
    float acc[NPAD] = {a0.x, a0.y, a0.z, a0.w, a1.x, a1.y, a1.z, a1.w,
                       a2.x, a2.y, a2.z, a2.w, a3.x, a3.y, a3.z, a3.w};

    const int lane = threadIdx.x & 63;
    const int wave = threadIdx.x >> 6;
    __shared__ float red[16][NPAD];
#pragma unroll
    for (int k = 0; k < NPAD; ++k) {
        float v = acc[k];
        for (int o = 32; o > 0; o >>= 1) v += __shfl_down(v, o, 64);
        if (lane == 0) red[wave][k] = v;
    }
    __syncthreads();
    if (threadIdx.x == 0) {
        float a[NACC];
#pragma unroll
        for (int k = 0; k < NACC; ++k) {
            float v = 0.f;
#pragma unroll
            for (int wv = 0; wv < 16; ++wv) v += red[wv][k];
            a[k] = v;
        }
        const float EPS = 1e-8f;
        const float M = a[0], Mx = a[1], My = a[2], Mz = a[3];
        const float dm = 3.f * M + EPS;
        float loss = (a[4] + a[5]) / dm;  // W_MAE=1, W_MSE=1
        loss += 0.1f   * (a[7] / (3.f * Mx + EPS) + a[8] / (3.f * My + EPS)
                        + a[9] / (3.f * Mz + EPS));
        loss += 0.002f * (a[10] / (3.f * Mx + EPS) + a[11] / (3.f * My + EPS)
                        + a[12] / (3.f * Mz + EPS));
        const float inv = 4194304.f - M;  // B*D*H*W - M
        loss += 0.15f * a[6] / (3.f * inv + EPS);
        out[0] = loss;
    }
}

extern "C" void kernel_launch(void* const* d_in, const int* in_sizes, int n_in,
                              void* d_out, int out_size, void* d_ws, size_t ws_size,
                              hipStream_t stream) {
    const float* pred   = (const float*)d_in[0];
    const float* target = (const float*)d_in[1];
    const float* mask   = (const float*)d_in[2];
    float* out      = (float*)d_out;
    float* partials = (float*)d_ws;  // NBLOCKS * NPAD floats = 128 KiB

    loss_main<<<NBLOCKS, 256, 0, stream>>>(pred, target, mask, partials);
    loss_final<<<1, 1024, 0, stream>>>(partials, out);
}